// Round 7
// baseline (236.567 us; speedup 1.0000x reference)
//
#include <hip/hip_runtime.h>
#include <math.h>

// Problem constants (fixed by the reference).
#define NUM_K   512        // codebook entries
#define DIM     64         // embedding dim (== C)
#define NROWS   131072     // 32*64*64 flattened (b,h,w) rows
#define NELEM   8388608    // NROWS*DIM
// d_out layout (float32, concatenated in return order):
// [0] loss ; [1..1+NELEM) quantized NCHW ; [1+NELEM] perplexity ;
// [2+NELEM..) codebook_indices (as float)
#define Q_OFF    1
#define PERP_OFF 8388609
#define IDX_OFF  8388610

// Candidate margin: approx-score error eps<=1.2e-5 (bf16 hi/lo MFMA, incl.
// dropped xl*wl), ref fp32 grid noise eta<=1.52e-5 -> need M > 2eps+2eta
// = 5.5e-5. M=1e-4 gives ~2x safety. Rows' ks with s' > s'min+M provably
// cannot be the reference argmin; candidates get frozen bitwise evaluation.
#define MARGIN  1.0e-4f

// LEDGER (hard facts only):
//  - launch_bounds min-waves >=4 clamps VGPR to 64 + scratch spill (r2,r4).
//  - TLP >> ILP for this kernel: 2x rows/wave (r6) = -44% throughput at
//    half the waves; leaner VALU (r1) also lost. Keep per-wave work at the
//    verified round-0 shape (32 rows x 512 codes) and maximize residency.
//  - Cross-session noise ~ +/-10us on totals; only >15% moves are signal.

typedef short  bf16x8 __attribute__((ext_vector_type(8)));
typedef float  f32x4  __attribute__((ext_vector_type(4)));

// ws layout (host-computed; REP = power-of-2 replica count for counts):
//   [0,4)                          float loss_sum
//   [8,12)                         uint  ticket
//   [64, 64+REP*2048)              uint  counts[REP][512]
//   [64+REP*2048, +2048)           float swsq_g[512]   (frozen ||w_k||^2)
//   [64+REP*2048+2048, +131072)    ushort wpack[65536] (B-frag hi/lo codebook)

__device__ __forceinline__ unsigned short f2bf(float f) {  // RNE f32->bf16
    unsigned u = __float_as_uint(f);
    return (unsigned short)((u + 0x7FFFu + ((u >> 16) & 1u)) >> 16);
}
__device__ __forceinline__ float bf2f(unsigned short h) {
    return __uint_as_float(((unsigned)h) << 16);
}

// Frozen bitwise reference score (verified): sequential fmaf chain c=0..63,
// s = fl(fl(xsq+wsq)-fl(2*dot)). Packed (bits(s)<<32)|k: s>0 always (~64),
// so u64 min = lexicographic (s,k) = np.argmin first-occurrence rule.
__device__ __forceinline__ unsigned long long eval_chain(
        const float* __restrict__ xr, float xsq,
        const float* __restrict__ w, float wsq, int k) {
    const float* wk = w + (size_t)k * DIM;
    float d = 0.f;
#pragma unroll
    for (int c = 0; c < DIM; c += 4) {
        float4 wv = *(const float4*)(wk + c);
        d = fmaf(xr[c + 0], wv.x, d);
        d = fmaf(xr[c + 1], wv.y, d);
        d = fmaf(xr[c + 2], wv.z, d);
        d = fmaf(xr[c + 3], wv.w, d);
    }
    float s = __fsub_rn(__fadd_rn(xsq, wsq), __fmul_rn(2.f, d));
    return ((unsigned long long)__float_as_uint(s) << 32) | (unsigned)k;
}

// Prep: frozen wsq + B-fragment hi/lo packing for mfma_f32_16x16x32_bf16
// (B[k=(lane>>4)*8+j][n=lane&15]). Also zeroes loss/ticket/counts.
__global__ __launch_bounds__(256) void vq_prep(const float* __restrict__ w,
                                               float* __restrict__ swsq_g,
                                               unsigned short* __restrict__ wpack,
                                               unsigned* __restrict__ counts,
                                               int rep_words,
                                               float* __restrict__ loss_sum,
                                               unsigned* __restrict__ ticket) {
    const int id = blockIdx.x * 256 + threadIdx.x;   // 0..8191
    if (id < rep_words) counts[id] = 0u;
    if (id == 0) { loss_sum[0] = 0.f; ticket[0] = 0u; }
    if (id < NUM_K) {
        const float* wk = w + id * DIM;
        float r[8];
#pragma unroll
        for (int j = 0; j < 8; ++j) r[j] = __fmul_rn(wk[j], wk[j]);
#pragma unroll
        for (int t = 1; t < 8; ++t)
#pragma unroll
            for (int j = 0; j < 8; ++j)
                r[j] = __fadd_rn(r[j], __fmul_rn(wk[8 * t + j], wk[8 * t + j]));
        swsq_g[id] = __fadd_rn(
            __fadd_rn(__fadd_rn(r[0], r[1]), __fadd_rn(r[2], r[3])),
            __fadd_rn(__fadd_rn(r[4], r[5]), __fadd_rn(r[6], r[7])));
    }
    const int kt = id >> 8, f = (id >> 6) & 3, l = id & 63;
    const int step = f >> 1, pass = f & 1;
    const int coln = kt * 16 + (l & 15), quad = l >> 4;
    const float* src = w + (size_t)coln * DIM + step * 32 + quad * 8;
    unsigned short tmp[8];
#pragma unroll
    for (int j = 0; j < 8; ++j) {
        float v = src[j];
        unsigned short hi = f2bf(v);
        tmp[j] = pass ? f2bf(v - bf2f(hi)) : hi;
    }
    *(uint4*)(wpack + (size_t)id * 8) = *(uint4*)tmp;
}

// Main kernel, round 7: 128-thread / 2-wave blocks, 64 rows each (2048
// blocks). Per-wave work is BITWISE the verified round-0 form (32 rows x
// 512 codes). LDS ~21.7 KB/block -> ~7 blocks/CU (~14 waves/CU), about
// 2x the wave residency of the 256-thread/39.4KB structure. Total wave
// count and per-wave loads unchanged chip-wide; only co-residency rises.
__global__ __launch_bounds__(128) void vq_phase1(
        const float* __restrict__ x,
        const float* __restrict__ w,
        const float* __restrict__ swsq_g,
        const uint4* __restrict__ wpack,
        float* __restrict__ out,
        float* __restrict__ loss_sum,
        unsigned* __restrict__ counts,
        unsigned* __restrict__ ticket,
        int rep_mask) {
    __shared__ float swsq[NUM_K];              // 2 KB
    __shared__ unsigned hcnt[NUM_K];           // 2 KB
    __shared__ float xs[64 * 65];              // x rows, stride 65: 16.6 KB
    __shared__ float sxsq[64];                 // frozen xsq per row
    __shared__ int sidx[64];                   // final index per row
    __shared__ float wred[2];
    __shared__ unsigned long long rred[2];
    __shared__ int rlist[64];
    __shared__ int rcount;
    __shared__ unsigned s_tick;
    __shared__ float red8[8];

    const int tid  = threadIdx.x;              // 0..127
    const int lane = tid & 63;
    const int wvid = tid >> 6;                 // 0..1
    const int quad = lane >> 4;
    const int m    = lane & 15;
    const int n0   = blockIdx.x * 64;          // 2048 tiles of 64 rows
    const int b    = n0 >> 12;                 // 64 | 4096: no straddle
    const int hw0  = n0 & 4095;
    const float* xbase = x + (size_t)b * 262144 + hw0;
    float* out_q   = out + Q_OFF;
    float* out_idx = out + IDX_OFF;

    if (tid == 0) rcount = 0;
    for (int i = tid; i < NUM_K; i += 128) { swsq[i] = swsq_g[i]; hcnt[i] = 0; }

    // Stage x -> xs (stride-65: conflict-free) + A fragments in registers.
    // 2 row-tiles per wave (32 rows) — round-0 verified form.
    bf16x8 afr[2][2][2];
#pragma unroll
    for (int rt = 0; rt < 2; ++rt) {
        const int row = wvid * 32 + rt * 16 + m;   // 0..63
        const float* xp = xbase + row;
#pragma unroll
        for (int s = 0; s < 2; ++s) {
            union { bf16x8 v; unsigned short u[8]; } hi, lo;
#pragma unroll
            for (int j = 0; j < 8; ++j) {
                const int c = s * 32 + quad * 8 + j;
                float v = xp[(size_t)c * 4096];
                xs[row * 65 + c] = v;
                unsigned short h = f2bf(v);
                hi.u[j] = h;
                lo.u[j] = f2bf(v - bf2f(h));
            }
            afr[rt][s][0] = hi.v;
            afr[rt][s][1] = lo.v;
        }
    }
    __syncthreads();   // xs ready

    // Frozen xsq per row (bitwise same per-row form as verified rounds).
    if (tid < 64) {
        const float* xr = &xs[tid * 65];
        float p0 = 0.f, p1 = 0.f, p2 = 0.f, p3 = 0.f;
#pragma unroll
        for (int c = 0; c < DIM; c += 4) {
            p0 = fmaf(xr[c + 0], xr[c + 0], p0);
            p1 = fmaf(xr[c + 1], xr[c + 1], p1);
            p2 = fmaf(xr[c + 2], xr[c + 2], p2);
            p3 = fmaf(xr[c + 3], xr[c + 3], p3);
        }
        sxsq[tid] = __fadd_rn(__fadd_rn(p0, p1), __fadd_rn(p2, p3));
    }
    __syncthreads();   // sxsq/swsq/rcount ready

    // Approx k-loop: track top-3 values + top-2 indices per lane-class.
    // (Round-0 verified form, bitwise unchanged.)
    float min1[2][4], min2[2][4], min3[2][4]; int idx1[2][4], idx2[2][4];
#pragma unroll
    for (int rt = 0; rt < 2; ++rt)
#pragma unroll
        for (int r = 0; r < 4; ++r) {
            min1[rt][r] = 3.4e38f; min2[rt][r] = 3.4e38f; min3[rt][r] = 3.4e38f;
            idx1[rt][r] = 0; idx2[rt][r] = 0;
        }

    uint4 P[2][4];
    {
        const uint4* t0 = wpack;
        const uint4* t1 = wpack + 256;
#pragma unroll
        for (int q = 0; q < 4; ++q) { P[0][q] = t0[q * 64 + lane];
                                      P[1][q] = t1[q * 64 + lane]; }
    }
#pragma unroll 1
    for (int kt = 0; kt < 32; kt += 2) {
#pragma unroll
        for (int h = 0; h < 2; ++h) {
            bf16x8 bh0 = __builtin_bit_cast(bf16x8, P[h][0]);
            bf16x8 bl0 = __builtin_bit_cast(bf16x8, P[h][1]);
            bf16x8 bh1 = __builtin_bit_cast(bf16x8, P[h][2]);
            bf16x8 bl1 = __builtin_bit_cast(bf16x8, P[h][3]);
            const int kg = (kt + h) * 16 + m;
            const float wsqv = swsq[kg];
            if (kt + h + 2 < 32) {
                const uint4* np = wpack + (size_t)(kt + h + 2) * 256;
#pragma unroll
                for (int q = 0; q < 4; ++q) P[h][q] = np[q * 64 + lane];
            }
#pragma unroll
            for (int rt = 0; rt < 2; ++rt) {
                f32x4 acc = {0.f, 0.f, 0.f, 0.f};
                acc = __builtin_amdgcn_mfma_f32_16x16x32_bf16(afr[rt][0][0], bh0, acc, 0, 0, 0);
                acc = __builtin_amdgcn_mfma_f32_16x16x32_bf16(afr[rt][0][0], bl0, acc, 0, 0, 0);
                acc = __builtin_amdgcn_mfma_f32_16x16x32_bf16(afr[rt][0][1], bh0, acc, 0, 0, 0);
                acc = __builtin_amdgcn_mfma_f32_16x16x32_bf16(afr[rt][1][0], bh1, acc, 0, 0, 0);
                acc = __builtin_amdgcn_mfma_f32_16x16x32_bf16(afr[rt][1][0], bl1, acc, 0, 0, 0);
                acc = __builtin_amdgcn_mfma_f32_16x16x32_bf16(afr[rt][1][1], bh1, acc, 0, 0, 0);
#pragma unroll
                for (int r = 0; r < 4; ++r) {
                    float s = fmaf(-2.f, acc[r], wsqv);
                    bool lt1 = s < min1[rt][r];
                    bool lt2 = s < min2[rt][r];
                    min3[rt][r] = __builtin_amdgcn_fmed3f(min2[rt][r], min3[rt][r], s);
                    idx2[rt][r] = lt1 ? idx1[rt][r] : (lt2 ? kg : idx2[rt][r]);
                    min2[rt][r] = __builtin_amdgcn_fmed3f(min1[rt][r], min2[rt][r], s);
                    idx1[rt][r] = lt1 ? kg : idx1[rt][r];
                    min1[rt][r] = fminf(min1[rt][r], s);
                }
            }
        }
    }

    // Per-rowslot resolution: gmin reduce, candidate exact chains, u64 reduce.
#pragma unroll 1
    for (int rt = 0; rt < 2; ++rt)
#pragma unroll 1
        for (int r = 0; r < 4; ++r) {
            float g1 = min1[rt][r]; int gi = idx1[rt][r];
#pragma unroll
            for (int d = 1; d < 16; d <<= 1) {
                float og = __shfl_xor(g1, d);
                int   oi = __shfl_xor(gi, d);
                if (og < g1) { g1 = og; gi = oi; }
            }
            const float lim = g1 + MARGIN;
            const bool c1 = min1[rt][r] <= lim;
            const bool c2 = min2[rt][r] <= lim;
            const bool f3 = min3[rt][r] <= lim;
            unsigned long long b1 = __ballot(c1);
            unsigned long long b2 = __ballot(c2);
            unsigned long long b3 = __ballot(f3);
            const unsigned fld1 = (unsigned)(b1 >> (quad * 16)) & 0xFFFFu;
            const unsigned fld2 = (unsigned)(b2 >> (quad * 16)) & 0xFFFFu;
            const unsigned fld3 = (unsigned)(b3 >> (quad * 16)) & 0xFFFFu;
            const int  nc   = __popc(fld1) + __popc(fld2);
            const bool flag = fld3 != 0;   // >=3 same-class within M: rescan
            const int rowL = wvid * 32 + rt * 16 + quad * 4 + r;   // 0..63
            unsigned long long best = ~0ull;
            if (!flag && nc > 1) {
                const float* xr = &xs[rowL * 65];
                const float xq = sxsq[rowL];
                const int k1 = c1 ? idx1[rt][r] : idx2[rt][r];
                if (c1 || c2) best = eval_chain(xr, xq, w, swsq[k1], k1);
                if (c1 && c2) {
                    unsigned long long e =
                        eval_chain(xr, xq, w, swsq[idx2[rt][r]], idx2[rt][r]);
                    best = e < best ? e : best;
                }
            }
#pragma unroll
            for (int d = 1; d < 16; d <<= 1) {
                unsigned long long o = __shfl_xor(best, d);
                best = o < best ? o : best;
            }
            if (m == 0) {
                if (flag) rlist[atomicAdd(&rcount, 1)] = rowL;
                else sidx[rowL] = (nc > 1) ? (int)(best & 0xFFFFFFFFull) : gi;
            }
        }
    __syncthreads();   // sidx (candidate path) + rlist/rcount ready

    // Full exact rescan for flagged rows (rare): whole block, 4 k/thread.
    // u64-min is commutative/associative -> same argmin as any order.
    const int rc = rcount;
#pragma unroll 1
    for (int i = 0; i < rc; ++i) {
        const int rowL = rlist[i];
        const float* xr = &xs[rowL * 65];
        const float xq = sxsq[rowL];
        unsigned long long bb = eval_chain(xr, xq, w, swsq[tid], tid);
        unsigned long long e1 = eval_chain(xr, xq, w, swsq[tid + 128], tid + 128);
        unsigned long long e2 = eval_chain(xr, xq, w, swsq[tid + 256], tid + 256);
        unsigned long long e3 = eval_chain(xr, xq, w, swsq[tid + 384], tid + 384);
        if (e1 < bb) bb = e1;
        if (e2 < bb) bb = e2;
        if (e3 < bb) bb = e3;
#pragma unroll
        for (int d = 1; d < 64; d <<= 1) {
            unsigned long long o = __shfl_xor(bb, d);
            if (o < bb) bb = o;
        }
        if (lane == 0) rred[wvid] = bb;
        __syncthreads();
        if (tid == 0) {
            unsigned long long q = rred[0] < rred[1] ? rred[0] : rred[1];
            sidx[rowL] = (int)(q & 0xFFFFFFFFull);
        }
        __syncthreads();
    }

    // Epilogue: thread (rb=tid&63, cg=tid>>6) handles 32 channels of row rb;
    // x from LDS (no global re-read). Per-thread op chain identical.
    {
        const int rb = tid & 63, cg = tid >> 6;
        const int bk = sidx[rb];
        const float* xr = &xs[rb * 65];
        float dsum = 0.f;
        const float4* wb = (const float4*)(w + (size_t)bk * DIM + cg * 32);
        float* oq = out_q + (size_t)b * 262144 + hw0 + rb;
        if (cg == 0) {
            out_idx[n0 + rb] = (float)bk;
            atomicAdd(&hcnt[bk], 1u);
        }
#pragma unroll
        for (int j4 = 0; j4 < 8; ++j4) {
            float4 v = wb[j4];
            const int c = cg * 32 + j4 * 4;
            float e0 = v.x - xr[c + 0];
            float e1 = v.y - xr[c + 1];
            float e2 = v.z - xr[c + 2];
            float e3 = v.w - xr[c + 3];
            dsum = fmaf(e0, e0, dsum);
            dsum = fmaf(e1, e1, dsum);
            dsum = fmaf(e2, e2, dsum);
            dsum = fmaf(e3, e3, dsum);
            oq[(size_t)(c + 0) * 4096] = v.x;
            oq[(size_t)(c + 1) * 4096] = v.y;
            oq[(size_t)(c + 2) * 4096] = v.z;
            oq[(size_t)(c + 3) * 4096] = v.w;
        }
#pragma unroll
        for (int off = 32; off > 0; off >>= 1) dsum += __shfl_down(dsum, off);
        if (lane == 0) wred[wvid] = dsum;
    }
    __syncthreads();
    if (tid == 0)
        atomicAdd(loss_sum, wred[0] + wred[1]);
    {
        unsigned* mycnt = counts + ((blockIdx.x & rep_mask) << 9);
        for (int i = tid; i < NUM_K; i += 128) {
            unsigned cc = hcnt[i];
            if (cc) atomicAdd(&mycnt[i], cc);
        }
    }

    // Ticket: the barrier's vmcnt(0) drain guarantees this block's counts/
    // loss atomics are acked at the coherent point before the ticket RMW.
    __syncthreads();
    if (tid == 0) s_tick = atomicAdd(ticket, 1u);
    __syncthreads();
    if (s_tick == (unsigned)(gridDim.x - 1)) {
        // Folded vq_final: bitwise-identical reduction tree (8 virtual
        // 64-lane waves, same shfl_down butterfly, same red8[] slotting
        // and serial 0..7 sum). 2 real waves x 4 half-iterations.
#pragma unroll 1
        for (int half = 0; half < 4; ++half) {
            const int vw = wvid + half * 2;     // 0..7
            const int k = vw * 64 + lane;
            unsigned cnt = 0;
            for (int rr = 0; rr <= rep_mask; ++rr)
                cnt += __hip_atomic_load(&counts[(rr << 9) + k],
                                         __ATOMIC_RELAXED,
                                         __HIP_MEMORY_SCOPE_AGENT);
            float p = (float)cnt * (1.f / (float)NROWS);  // /131072 exact
            float t = p * logf(p + 1e-10f);
#pragma unroll
            for (int off = 32; off > 0; off >>= 1) t += __shfl_down(t, off);
            if (lane == 0) red8[vw] = t;
        }
        __syncthreads();
        if (tid == 0) {
            float s = 0.f;
#pragma unroll
            for (int i = 0; i < 8; ++i) s += red8[i];
            out[PERP_OFF] = expf(-s);
            // loss = q_latent + 0.25*e_latent = 1.25 * MSE (forward equal)
            float ls = __hip_atomic_load(loss_sum, __ATOMIC_RELAXED,
                                         __HIP_MEMORY_SCOPE_AGENT);
            out[0] = ls * (1.25f / (float)NELEM);
        }
    }
}

extern "C" void kernel_launch(void* const* d_in, const int* in_sizes, int n_in,
                              void* d_out, int out_size, void* d_ws, size_t ws_size,
                              hipStream_t stream) {
    const float* x = (const float*)d_in[0];
    const float* w = (const float*)d_in[1];
    float* out = (float*)d_out;
    char* ws = (char*)d_ws;

    // Histogram replica count: as many as fit (power of 2, <=16). rep=2
    // footprint (137280 B) <= the round-0 kernel's workspace use, so this
    // always fits a workspace the old kernel ran in.
    int rep = 16;
    while (rep > 2 && (size_t)(64 + rep * 2048 + 2048 + 131072) > ws_size)
        rep >>= 1;

    float*    loss_sum = (float*)ws;
    unsigned* ticket   = (unsigned*)(ws + 8);
    unsigned* counts   = (unsigned*)(ws + 64);
    float*    swsq_g   = (float*)(ws + 64 + rep * 2048);
    unsigned short* wpack = (unsigned short*)(ws + 64 + rep * 2048 + 2048);

    // No memset dispatch: vq_prep zeroes loss/ticket/counts.
    vq_prep<<<32, 256, 0, stream>>>(w, swsq_g, wpack, counts, rep * 512,
                                    loss_sum, ticket);
    // 2048 blocks x 128 threads, 64 rows each: ~7 blocks/CU (LDS ~21.7 KB).
    vq_phase1<<<NROWS / 64, 128, 0, stream>>>(x, w, swsq_g, (const uint4*)wpack,
                                              out, loss_sum, counts, ticket,
                                              rep - 1);
}

// Round 8
// 163.714 us; speedup vs baseline: 1.4450x; 1.4450x over previous
//
#include <hip/hip_runtime.h>
#include <math.h>

// Problem constants (fixed by the reference).
#define NUM_K   512        // codebook entries
#define DIM     64         // embedding dim (== C)
#define NROWS   131072     // 32*64*64 flattened (b,h,w) rows
#define NELEM   8388608    // NROWS*DIM
// d_out layout (float32, concatenated in return order):
// [0] loss ; [1..1+NELEM) quantized NCHW ; [1+NELEM] perplexity ;
// [2+NELEM..) codebook_indices (as float)
#define Q_OFF    1
#define PERP_OFF 8388609
#define IDX_OFF  8388610

// Candidate margin: approx-score error eps<=1.2e-5 (bf16 hi/lo MFMA, incl.
// dropped xl*wl), ref fp32 grid noise eta<=1.52e-5 -> need M > 2eps+2eta
// = 5.5e-5. M=1e-4 gives ~2x safety. Rows' ks with s' > s'min+M provably
// cannot be the reference argmin; candidates get frozen bitwise evaluation.
#define MARGIN  1.0e-4f

// LEDGER (hard facts):
//  - launch_bounds min-waves >=4 clamps VGPR to 64 + scratch spill (r2,r4).
//  - bare launch_bounds on small blocks lets VGPR balloon (r7: 148).
//    (256,3) reliably gives ~84 VGPR, no spill. Keep it.
//  - Round-0 per-wave shape (32 rows x 512 codes, 4-wave 256-thr blocks)
//    beat every variant: ILP x2 (r6 -44%), leaner VALU (r1), blocks/2
//    (r7), swizzle (r3). Latency plateau: all pipes <40%, occ ~21%.
//  - Cross-session total noise ~ +/-10-18us; trust phase1 counters only.

typedef short  bf16x8 __attribute__((ext_vector_type(8)));
typedef float  f32x4  __attribute__((ext_vector_type(4)));

// ws layout (host-computed; REP = power-of-2 replica count for counts, <=8):
//   [0,4)                          float loss_sum
//   [8,12)                         uint  ticket
//   [64, 64+REP*2048)              uint  counts[REP][512]
//   [64+REP*2048, +2048)           float swsq_g[512]   (frozen ||w_k||^2)
//   [64+REP*2048+2048, +131072)    ushort wpack[65536] (B-frag hi/lo codebook)

__device__ __forceinline__ unsigned short f2bf(float f) {  // RNE f32->bf16
    unsigned u = __float_as_uint(f);
    return (unsigned short)((u + 0x7FFFu + ((u >> 16) & 1u)) >> 16);
}
__device__ __forceinline__ float bf2f(unsigned short h) {
    return __uint_as_float(((unsigned)h) << 16);
}

// Frozen bitwise reference score (verified): sequential fmaf chain c=0..63,
// s = fl(fl(xsq+wsq)-fl(2*dot)). Packed (bits(s)<<32)|k: s>0 always (~64),
// so u64 min = lexicographic (s,k) = np.argmin first-occurrence rule.
__device__ __forceinline__ unsigned long long eval_chain(
        const float* __restrict__ xr, float xsq,
        const float* __restrict__ w, float wsq, int k) {
    const float* wk = w + (size_t)k * DIM;
    float d = 0.f;
#pragma unroll
    for (int c = 0; c < DIM; c += 4) {
        float4 wv = *(const float4*)(wk + c);
        d = fmaf(xr[c + 0], wv.x, d);
        d = fmaf(xr[c + 1], wv.y, d);
        d = fmaf(xr[c + 2], wv.z, d);
        d = fmaf(xr[c + 3], wv.w, d);
    }
    float s = __fsub_rn(__fadd_rn(xsq, wsq), __fmul_rn(2.f, d));
    return ((unsigned long long)__float_as_uint(s) << 32) | (unsigned)k;
}

// Prep: frozen wsq + B-fragment hi/lo packing for mfma_f32_16x16x32_bf16
// (B[k=(lane>>4)*8+j][n=lane&15]). Also zeroes loss/ticket/counts.
__global__ __launch_bounds__(256) void vq_prep(const float* __restrict__ w,
                                               float* __restrict__ swsq_g,
                                               unsigned short* __restrict__ wpack,
                                               unsigned* __restrict__ counts,
                                               int rep_words,
                                               float* __restrict__ loss_sum,
                                               unsigned* __restrict__ ticket) {
    const int id = blockIdx.x * 256 + threadIdx.x;   // 0..8191
    if (id < rep_words) counts[id] = 0u;
    if (id == 0) { loss_sum[0] = 0.f; ticket[0] = 0u; }
    if (id < NUM_K) {
        const float* wk = w + id * DIM;
        float r[8];
#pragma unroll
        for (int j = 0; j < 8; ++j) r[j] = __fmul_rn(wk[j], wk[j]);
#pragma unroll
        for (int t = 1; t < 8; ++t)
#pragma unroll
            for (int j = 0; j < 8; ++j)
                r[j] = __fadd_rn(r[j], __fmul_rn(wk[8 * t + j], wk[8 * t + j]));
        swsq_g[id] = __fadd_rn(
            __fadd_rn(__fadd_rn(r[0], r[1]), __fadd_rn(r[2], r[3])),
            __fadd_rn(__fadd_rn(r[4], r[5]), __fadd_rn(r[6], r[7])));
    }
    const int kt = id >> 8, f = (id >> 6) & 3, l = id & 63;
    const int step = f >> 1, pass = f & 1;
    const int coln = kt * 16 + (l & 15), quad = l >> 4;
    const float* src = w + (size_t)coln * DIM + step * 32 + quad * 8;
    unsigned short tmp[8];
#pragma unroll
    for (int j = 0; j < 8; ++j) {
        float v = src[j];
        unsigned short hi = f2bf(v);
        tmp[j] = pass ? f2bf(v - bf2f(hi)) : hi;
    }
    *(uint4*)(wpack + (size_t)id * 8) = *(uint4*)tmp;
}

// Main kernel: consolidated best-evidence form. Round-0 verified MFMA
// approx pass (top-3 per lane, idx tracking) -> in-block frozen exact
// evaluation of candidates -> rare full rescans -> epilogue with DIRECT
// per-row replica histogram atomics (hcnt LDS histogram removed) ->
// fused final reduction via atomic ticket.
__global__ __launch_bounds__(256, 3) void vq_phase1(
        const float* __restrict__ x,
        const float* __restrict__ w,
        const float* __restrict__ swsq_g,
        const uint4* __restrict__ wpack,
        float* __restrict__ out,
        float* __restrict__ loss_sum,
        unsigned* __restrict__ counts,
        unsigned* __restrict__ ticket,
        int rep_mask) {
    __shared__ float swsq[NUM_K];              // 2 KB
    __shared__ float xs[128 * 65];             // x rows, stride 65: 33.3 KB
    __shared__ float sxsq[128];                // frozen xsq per row
    __shared__ int sidx[128];                  // final index per row
    __shared__ float wred[4];
    __shared__ unsigned long long rred[4];
    __shared__ int rlist[128];
    __shared__ int rcount;
    __shared__ unsigned s_tick;
    __shared__ float red8[8];

    const int tid  = threadIdx.x;
    const int lane = tid & 63;
    const int wvid = tid >> 6;
    const int quad = lane >> 4;
    const int m    = lane & 15;
    const int n0   = blockIdx.x * 128;
    const int b    = n0 >> 12;
    const int hw0  = n0 & 4095;
    const float* xbase = x + (size_t)b * 262144 + hw0;
    float* out_q   = out + Q_OFF;
    float* out_idx = out + IDX_OFF;

    if (tid == 0) rcount = 0;
    for (int i = tid; i < NUM_K; i += 256) swsq[i] = swsq_g[i];

    // Stage x -> xs (stride-65: conflict-free) + A fragments in registers.
    bf16x8 afr[2][2][2];
#pragma unroll
    for (int rt = 0; rt < 2; ++rt) {
        const int row = wvid * 32 + rt * 16 + m;
        const float* xp = xbase + row;
#pragma unroll
        for (int s = 0; s < 2; ++s) {
            union { bf16x8 v; unsigned short u[8]; } hi, lo;
#pragma unroll
            for (int j = 0; j < 8; ++j) {
                const int c = s * 32 + quad * 8 + j;
                float v = xp[(size_t)c * 4096];
                xs[row * 65 + c] = v;
                unsigned short h = f2bf(v);
                hi.u[j] = h;
                lo.u[j] = f2bf(v - bf2f(h));
            }
            afr[rt][s][0] = hi.v;
            afr[rt][s][1] = lo.v;
        }
    }
    __syncthreads();   // xs ready

    // Frozen xsq per row (bitwise same form as verified rounds).
    if (tid < 128) {
        const float* xr = &xs[tid * 65];
        float p0 = 0.f, p1 = 0.f, p2 = 0.f, p3 = 0.f;
#pragma unroll
        for (int c = 0; c < DIM; c += 4) {
            p0 = fmaf(xr[c + 0], xr[c + 0], p0);
            p1 = fmaf(xr[c + 1], xr[c + 1], p1);
            p2 = fmaf(xr[c + 2], xr[c + 2], p2);
            p3 = fmaf(xr[c + 3], xr[c + 3], p3);
        }
        sxsq[tid] = __fadd_rn(__fadd_rn(p0, p1), __fadd_rn(p2, p3));
    }
    __syncthreads();   // sxsq/swsq/rcount ready

    // Approx k-loop: track top-3 values + top-2 indices per lane-class.
    // (Round-0 verified form, bitwise unchanged.)
    float min1[2][4], min2[2][4], min3[2][4]; int idx1[2][4], idx2[2][4];
#pragma unroll
    for (int rt = 0; rt < 2; ++rt)
#pragma unroll
        for (int r = 0; r < 4; ++r) {
            min1[rt][r] = 3.4e38f; min2[rt][r] = 3.4e38f; min3[rt][r] = 3.4e38f;
            idx1[rt][r] = 0; idx2[rt][r] = 0;
        }

    uint4 P[2][4];
    {
        const uint4* t0 = wpack;
        const uint4* t1 = wpack + 256;
#pragma unroll
        for (int q = 0; q < 4; ++q) { P[0][q] = t0[q * 64 + lane];
                                      P[1][q] = t1[q * 64 + lane]; }
    }
#pragma unroll 1
    for (int kt = 0; kt < 32; kt += 2) {
#pragma unroll
        for (int h = 0; h < 2; ++h) {
            bf16x8 bh0 = __builtin_bit_cast(bf16x8, P[h][0]);
            bf16x8 bl0 = __builtin_bit_cast(bf16x8, P[h][1]);
            bf16x8 bh1 = __builtin_bit_cast(bf16x8, P[h][2]);
            bf16x8 bl1 = __builtin_bit_cast(bf16x8, P[h][3]);
            const int kg = (kt + h) * 16 + m;
            const float wsqv = swsq[kg];
            if (kt + h + 2 < 32) {
                const uint4* np = wpack + (size_t)(kt + h + 2) * 256;
#pragma unroll
                for (int q = 0; q < 4; ++q) P[h][q] = np[q * 64 + lane];
            }
#pragma unroll
            for (int rt = 0; rt < 2; ++rt) {
                f32x4 acc = {0.f, 0.f, 0.f, 0.f};
                acc = __builtin_amdgcn_mfma_f32_16x16x32_bf16(afr[rt][0][0], bh0, acc, 0, 0, 0);
                acc = __builtin_amdgcn_mfma_f32_16x16x32_bf16(afr[rt][0][0], bl0, acc, 0, 0, 0);
                acc = __builtin_amdgcn_mfma_f32_16x16x32_bf16(afr[rt][0][1], bh0, acc, 0, 0, 0);
                acc = __builtin_amdgcn_mfma_f32_16x16x32_bf16(afr[rt][1][0], bh1, acc, 0, 0, 0);
                acc = __builtin_amdgcn_mfma_f32_16x16x32_bf16(afr[rt][1][0], bl1, acc, 0, 0, 0);
                acc = __builtin_amdgcn_mfma_f32_16x16x32_bf16(afr[rt][1][1], bh1, acc, 0, 0, 0);
#pragma unroll
                for (int r = 0; r < 4; ++r) {
                    float s = fmaf(-2.f, acc[r], wsqv);
                    bool lt1 = s < min1[rt][r];
                    bool lt2 = s < min2[rt][r];
                    min3[rt][r] = __builtin_amdgcn_fmed3f(min2[rt][r], min3[rt][r], s);
                    idx2[rt][r] = lt1 ? idx1[rt][r] : (lt2 ? kg : idx2[rt][r]);
                    min2[rt][r] = __builtin_amdgcn_fmed3f(min1[rt][r], min2[rt][r], s);
                    idx1[rt][r] = lt1 ? kg : idx1[rt][r];
                    min1[rt][r] = fminf(min1[rt][r], s);
                }
            }
        }
    }

    // Per-rowslot resolution: gmin reduce, candidate exact chains, u64 reduce.
#pragma unroll 1
    for (int rt = 0; rt < 2; ++rt)
#pragma unroll 1
        for (int r = 0; r < 4; ++r) {
            float g1 = min1[rt][r]; int gi = idx1[rt][r];
#pragma unroll
            for (int d = 1; d < 16; d <<= 1) {
                float og = __shfl_xor(g1, d);
                int   oi = __shfl_xor(gi, d);
                if (og < g1) { g1 = og; gi = oi; }
            }
            const float lim = g1 + MARGIN;
            const bool c1 = min1[rt][r] <= lim;
            const bool c2 = min2[rt][r] <= lim;
            const bool f3 = min3[rt][r] <= lim;
            unsigned long long b1 = __ballot(c1);
            unsigned long long b2 = __ballot(c2);
            unsigned long long b3 = __ballot(f3);
            const unsigned fld1 = (unsigned)(b1 >> (quad * 16)) & 0xFFFFu;
            const unsigned fld2 = (unsigned)(b2 >> (quad * 16)) & 0xFFFFu;
            const unsigned fld3 = (unsigned)(b3 >> (quad * 16)) & 0xFFFFu;
            const int  nc   = __popc(fld1) + __popc(fld2);
            const bool flag = fld3 != 0;   // >=3 same-class within M: rescan
            const int rowL = wvid * 32 + rt * 16 + quad * 4 + r;
            unsigned long long best = ~0ull;
            if (!flag && nc > 1) {
                const float* xr = &xs[rowL * 65];
                const float xq = sxsq[rowL];
                const int k1 = c1 ? idx1[rt][r] : idx2[rt][r];
                if (c1 || c2) best = eval_chain(xr, xq, w, swsq[k1], k1);
                if (c1 && c2) {
                    unsigned long long e =
                        eval_chain(xr, xq, w, swsq[idx2[rt][r]], idx2[rt][r]);
                    best = e < best ? e : best;
                }
            }
#pragma unroll
            for (int d = 1; d < 16; d <<= 1) {
                unsigned long long o = __shfl_xor(best, d);
                best = o < best ? o : best;
            }
            if (m == 0) {
                if (flag) rlist[atomicAdd(&rcount, 1)] = rowL;
                else sidx[rowL] = (nc > 1) ? (int)(best & 0xFFFFFFFFull) : gi;
            }
        }
    __syncthreads();   // sidx (candidate path) + rlist/rcount ready

    // Full exact rescan for flagged rows (rare, ~0.3%): whole block, 2 k/thr.
    const int rc = rcount;
#pragma unroll 1
    for (int i = 0; i < rc; ++i) {
        const int rowL = rlist[i];
        const float* xr = &xs[rowL * 65];
        const float xq = sxsq[rowL];
        unsigned long long bb = eval_chain(xr, xq, w, swsq[tid], tid);
        unsigned long long e2 = eval_chain(xr, xq, w, swsq[tid + 256], tid + 256);
        if (e2 < bb) bb = e2;
#pragma unroll
        for (int d = 1; d < 64; d <<= 1) {
            unsigned long long o = __shfl_xor(bb, d);
            if (o < bb) bb = o;
        }
        if (lane == 0) rred[wvid] = bb;
        __syncthreads();
        if (tid == 0) {
            unsigned long long q0 = rred[0] < rred[1] ? rred[0] : rred[1];
            unsigned long long q1 = rred[2] < rred[3] ? rred[2] : rred[3];
            sidx[rowL] = (int)((q0 < q1 ? q0 : q1) & 0xFFFFFFFFull);
        }
        __syncthreads();
    }

    // Epilogue: thread (rb=tid&127, cg=tid>>7) handles 32 channels of row rb;
    // x from LDS (no global re-read). Histogram: ONE direct atomic per row
    // to this block's replica (hcnt LDS histogram + 512-entry flush removed).
    {
        const int rb = tid & 127, cg = tid >> 7;
        const int bk = sidx[rb];
        const float* xr = &xs[rb * 65];
        float dsum = 0.f;
        const float4* wb = (const float4*)(w + (size_t)bk * DIM + cg * 32);
        float* oq = out_q + (size_t)b * 262144 + hw0 + rb;
        if (cg == 0) {
            out_idx[n0 + rb] = (float)bk;
            atomicAdd(&counts[((blockIdx.x & rep_mask) << 9) + bk], 1u);
        }
#pragma unroll
        for (int j4 = 0; j4 < 8; ++j4) {
            float4 v = wb[j4];
            const int c = cg * 32 + j4 * 4;
            float e0 = v.x - xr[c + 0];
            float e1 = v.y - xr[c + 1];
            float e2 = v.z - xr[c + 2];
            float e3 = v.w - xr[c + 3];
            dsum = fmaf(e0, e0, dsum);
            dsum = fmaf(e1, e1, dsum);
            dsum = fmaf(e2, e2, dsum);
            dsum = fmaf(e3, e3, dsum);
            oq[(size_t)(c + 0) * 4096] = v.x;
            oq[(size_t)(c + 1) * 4096] = v.y;
            oq[(size_t)(c + 2) * 4096] = v.z;
            oq[(size_t)(c + 3) * 4096] = v.w;
        }
#pragma unroll
        for (int off = 32; off > 0; off >>= 1) dsum += __shfl_down(dsum, off);
        if (lane == 0) wred[wvid] = dsum;
    }
    __syncthreads();
    if (tid == 0)
        atomicAdd(loss_sum, (wred[0] + wred[1]) + (wred[2] + wred[3]));

    // Ticket: the barrier's vmcnt(0) drain guarantees this block's counts/
    // loss atomics are acked at the coherent point before the ticket RMW.
    __syncthreads();
    if (tid == 0) s_tick = atomicAdd(ticket, 1u);
    __syncthreads();
    if (s_tick == (unsigned)(gridDim.x - 1)) {
        // Folded vq_final: bitwise-identical reduction tree (8 virtual
        // 64-lane waves, same shfl_down butterfly, same red8 slotting and
        // serial 0..7 sum). Replica reads via relaxed AGENT-scope atomic
        // loads: coherent (bypass stale local caches) but pipelineable.
#pragma unroll 1
        for (int half = 0; half < 2; ++half) {
            const int k = (wvid + half * 4) * 64 + lane;
            unsigned cnt = 0;
            for (int rr = 0; rr <= rep_mask; ++rr)
                cnt += __hip_atomic_load(&counts[(rr << 9) + k],
                                         __ATOMIC_RELAXED,
                                         __HIP_MEMORY_SCOPE_AGENT);
            float p = (float)cnt * (1.f / (float)NROWS);  // /131072 exact
            float t = p * logf(p + 1e-10f);
#pragma unroll
            for (int off = 32; off > 0; off >>= 1) t += __shfl_down(t, off);
            if (lane == 0) red8[wvid + half * 4] = t;
        }
        __syncthreads();
        if (tid == 0) {
            float s = 0.f;
#pragma unroll
            for (int i = 0; i < 8; ++i) s += red8[i];
            out[PERP_OFF] = expf(-s);
            // loss = q_latent + 0.25*e_latent = 1.25 * MSE (forward equal)
            float ls = __hip_atomic_load(loss_sum, __ATOMIC_RELAXED,
                                         __HIP_MEMORY_SCOPE_AGENT);
            out[0] = ls * (1.25f / (float)NELEM);
        }
    }
}

extern "C" void kernel_launch(void* const* d_in, const int* in_sizes, int n_in,
                              void* d_out, int out_size, void* d_ws, size_t ws_size,
                              hipStream_t stream) {
    const float* x = (const float*)d_in[0];
    const float* w = (const float*)d_in[1];
    float* out = (float*)d_out;
    char* ws = (char*)d_ws;

    // Histogram replica count: 8 (= XCD count; replica r only touched by
    // XCD r under round-robin dispatch). Degrade to 4/2 if workspace is
    // tight; rep=2 footprint (137280 B) matches the round-0 kernel's use.
    int rep = 8;
    while (rep > 2 && (size_t)(64 + rep * 2048 + 2048 + 131072) > ws_size)
        rep >>= 1;

    float*    loss_sum = (float*)ws;
    unsigned* ticket   = (unsigned*)(ws + 8);
    unsigned* counts   = (unsigned*)(ws + 64);
    float*    swsq_g   = (float*)(ws + 64 + rep * 2048);
    unsigned short* wpack = (unsigned short*)(ws + 64 + rep * 2048 + 2048);

    // No memset dispatch: vq_prep zeroes loss/ticket/counts.
    vq_prep<<<32, 256, 0, stream>>>(w, swsq_g, wpack, counts, rep * 512,
                                    loss_sum, ticket);
    vq_phase1<<<NROWS / 128, 256, 0, stream>>>(x, w, swsq_g, (const uint4*)wpack,
                                               out, loss_sum, counts, ticket,
                                               rep - 1);
}

// Round 9
// 157.166 us; speedup vs baseline: 1.5052x; 1.0417x over previous
//
#include <hip/hip_runtime.h>
#include <math.h>

// Problem constants (fixed by the reference).
#define NUM_K   512        // codebook entries
#define DIM     64         // embedding dim (== C)
#define NROWS   131072     // 32*64*64 flattened (b,h,w) rows
#define NELEM   8388608    // NROWS*DIM
// d_out layout (float32, concatenated in return order):
// [0] loss ; [1..1+NELEM) quantized NCHW ; [1+NELEM] perplexity ;
// [2+NELEM..) codebook_indices (as float)
#define Q_OFF    1
#define PERP_OFF 8388609
#define IDX_OFF  8388610

// Candidate margin: approx-score error eps<=1.2e-5 (bf16 hi/lo MFMA, incl.
// dropped xl*wl), ref fp32 grid noise eta<=1.52e-5 -> need M > 2eps+2eta
// = 5.5e-5. M=1e-4 gives ~2x safety. Rows' ks with s' > s'min+M provably
// cannot be the reference argmin; candidates get frozen bitwise evaluation.
#define MARGIN  1.0e-4f

// LEDGER (hard facts):
//  - launch_bounds min-waves >=4 clamps VGPR to 64 + scratch spill (r2,r4);
//    bare launch_bounds lets VGPR balloon (r7: 148). (256,3) -> 84, stable.
//  - Round-0 per-wave shape (32 rows x 512 codes, 4-wave 256-thr blocks)
//    beat every structural variant (r1,r2,r3,r4,r6,r7).
//  - phase1 decomposition (r0/r5/r8 steady-state): fused final tail = +10us
//    on phase1 critical path; hcnt LDS histogram = +5us vs direct atomics.
//    This round: separate final dispatch + direct atomics (untested combo).
//  - Totals carry +/-20us harness noise; trust phase1 counters only.

typedef short  bf16x8 __attribute__((ext_vector_type(8)));
typedef float  f32x4  __attribute__((ext_vector_type(4)));

// ws layout (host-computed; REP = power-of-2 replica count for counts, <=8):
//   [0,4)                          float loss_sum
//   [64, 64+REP*2048)              uint  counts[REP][512]
//   [64+REP*2048, +2048)           float swsq_g[512]   (frozen ||w_k||^2)
//   [64+REP*2048+2048, +131072)    ushort wpack[65536] (B-frag hi/lo codebook)

__device__ __forceinline__ unsigned short f2bf(float f) {  // RNE f32->bf16
    unsigned u = __float_as_uint(f);
    return (unsigned short)((u + 0x7FFFu + ((u >> 16) & 1u)) >> 16);
}
__device__ __forceinline__ float bf2f(unsigned short h) {
    return __uint_as_float(((unsigned)h) << 16);
}

// Frozen bitwise reference score (verified): sequential fmaf chain c=0..63,
// s = fl(fl(xsq+wsq)-fl(2*dot)). Packed (bits(s)<<32)|k: s>0 always (~64),
// so u64 min = lexicographic (s,k) = np.argmin first-occurrence rule.
__device__ __forceinline__ unsigned long long eval_chain(
        const float* __restrict__ xr, float xsq,
        const float* __restrict__ w, float wsq, int k) {
    const float* wk = w + (size_t)k * DIM;
    float d = 0.f;
#pragma unroll
    for (int c = 0; c < DIM; c += 4) {
        float4 wv = *(const float4*)(wk + c);
        d = fmaf(xr[c + 0], wv.x, d);
        d = fmaf(xr[c + 1], wv.y, d);
        d = fmaf(xr[c + 2], wv.z, d);
        d = fmaf(xr[c + 3], wv.w, d);
    }
    float s = __fsub_rn(__fadd_rn(xsq, wsq), __fmul_rn(2.f, d));
    return ((unsigned long long)__float_as_uint(s) << 32) | (unsigned)k;
}

// Prep: frozen wsq + B-fragment hi/lo packing for mfma_f32_16x16x32_bf16
// (B[k=(lane>>4)*8+j][n=lane&15]). Also zeroes loss/counts (no memset
// dispatch needed).
__global__ __launch_bounds__(256) void vq_prep(const float* __restrict__ w,
                                               float* __restrict__ swsq_g,
                                               unsigned short* __restrict__ wpack,
                                               unsigned* __restrict__ counts,
                                               int rep_words,
                                               float* __restrict__ loss_sum) {
    const int id = blockIdx.x * 256 + threadIdx.x;   // 0..8191
    if (id < rep_words) counts[id] = 0u;
    if (id == 0) loss_sum[0] = 0.f;
    if (id < NUM_K) {
        const float* wk = w + id * DIM;
        float r[8];
#pragma unroll
        for (int j = 0; j < 8; ++j) r[j] = __fmul_rn(wk[j], wk[j]);
#pragma unroll
        for (int t = 1; t < 8; ++t)
#pragma unroll
            for (int j = 0; j < 8; ++j)
                r[j] = __fadd_rn(r[j], __fmul_rn(wk[8 * t + j], wk[8 * t + j]));
        swsq_g[id] = __fadd_rn(
            __fadd_rn(__fadd_rn(r[0], r[1]), __fadd_rn(r[2], r[3])),
            __fadd_rn(__fadd_rn(r[4], r[5]), __fadd_rn(r[6], r[7])));
    }
    const int kt = id >> 8, f = (id >> 6) & 3, l = id & 63;
    const int step = f >> 1, pass = f & 1;
    const int coln = kt * 16 + (l & 15), quad = l >> 4;
    const float* src = w + (size_t)coln * DIM + step * 32 + quad * 8;
    unsigned short tmp[8];
#pragma unroll
    for (int j = 0; j < 8; ++j) {
        float v = src[j];
        unsigned short hi = f2bf(v);
        tmp[j] = pass ? f2bf(v - bf2f(hi)) : hi;
    }
    *(uint4*)(wpack + (size_t)id * 8) = *(uint4*)tmp;
}

// Main kernel: round-0 verified MFMA approx pass (top-3 per lane, idx
// tracking) -> in-block frozen exact evaluation of candidates -> rare full
// rescans -> epilogue with DIRECT per-row replica histogram atomics.
// NO fused final tail (r0/r5/r8 decomposition: it cost ~10us of phase1
// critical path; the separate dispatch hides it in the pipeline).
__global__ __launch_bounds__(256, 3) void vq_phase1(
        const float* __restrict__ x,
        const float* __restrict__ w,
        const float* __restrict__ swsq_g,
        const uint4* __restrict__ wpack,
        float* __restrict__ out,
        float* __restrict__ loss_sum,
        unsigned* __restrict__ counts,
        int rep_mask) {
    __shared__ float swsq[NUM_K];              // 2 KB
    __shared__ float xs[128 * 65];             // x rows, stride 65: 33.3 KB
    __shared__ float sxsq[128];                // frozen xsq per row
    __shared__ int sidx[128];                  // final index per row
    __shared__ float wred[4];
    __shared__ unsigned long long rred[4];
    __shared__ int rlist[128];
    __shared__ int rcount;

    const int tid  = threadIdx.x;
    const int lane = tid & 63;
    const int wvid = tid >> 6;
    const int quad = lane >> 4;
    const int m    = lane & 15;
    const int n0   = blockIdx.x * 128;
    const int b    = n0 >> 12;
    const int hw0  = n0 & 4095;
    const float* xbase = x + (size_t)b * 262144 + hw0;
    float* out_q   = out + Q_OFF;
    float* out_idx = out + IDX_OFF;

    if (tid == 0) rcount = 0;
    for (int i = tid; i < NUM_K; i += 256) swsq[i] = swsq_g[i];

    // Stage x -> xs (stride-65: conflict-free) + A fragments in registers.
    bf16x8 afr[2][2][2];
#pragma unroll
    for (int rt = 0; rt < 2; ++rt) {
        const int row = wvid * 32 + rt * 16 + m;
        const float* xp = xbase + row;
#pragma unroll
        for (int s = 0; s < 2; ++s) {
            union { bf16x8 v; unsigned short u[8]; } hi, lo;
#pragma unroll
            for (int j = 0; j < 8; ++j) {
                const int c = s * 32 + quad * 8 + j;
                float v = xp[(size_t)c * 4096];
                xs[row * 65 + c] = v;
                unsigned short h = f2bf(v);
                hi.u[j] = h;
                lo.u[j] = f2bf(v - bf2f(h));
            }
            afr[rt][s][0] = hi.v;
            afr[rt][s][1] = lo.v;
        }
    }
    __syncthreads();   // xs ready

    // Frozen xsq per row (bitwise same form as verified rounds).
    if (tid < 128) {
        const float* xr = &xs[tid * 65];
        float p0 = 0.f, p1 = 0.f, p2 = 0.f, p3 = 0.f;
#pragma unroll
        for (int c = 0; c < DIM; c += 4) {
            p0 = fmaf(xr[c + 0], xr[c + 0], p0);
            p1 = fmaf(xr[c + 1], xr[c + 1], p1);
            p2 = fmaf(xr[c + 2], xr[c + 2], p2);
            p3 = fmaf(xr[c + 3], xr[c + 3], p3);
        }
        sxsq[tid] = __fadd_rn(__fadd_rn(p0, p1), __fadd_rn(p2, p3));
    }
    __syncthreads();   // sxsq/swsq/rcount ready

    // Approx k-loop: track top-3 values + top-2 indices per lane-class.
    // (Round-0 verified form, bitwise unchanged.)
    float min1[2][4], min2[2][4], min3[2][4]; int idx1[2][4], idx2[2][4];
#pragma unroll
    for (int rt = 0; rt < 2; ++rt)
#pragma unroll
        for (int r = 0; r < 4; ++r) {
            min1[rt][r] = 3.4e38f; min2[rt][r] = 3.4e38f; min3[rt][r] = 3.4e38f;
            idx1[rt][r] = 0; idx2[rt][r] = 0;
        }

    uint4 P[2][4];
    {
        const uint4* t0 = wpack;
        const uint4* t1 = wpack + 256;
#pragma unroll
        for (int q = 0; q < 4; ++q) { P[0][q] = t0[q * 64 + lane];
                                      P[1][q] = t1[q * 64 + lane]; }
    }
#pragma unroll 1
    for (int kt = 0; kt < 32; kt += 2) {
#pragma unroll
        for (int h = 0; h < 2; ++h) {
            bf16x8 bh0 = __builtin_bit_cast(bf16x8, P[h][0]);
            bf16x8 bl0 = __builtin_bit_cast(bf16x8, P[h][1]);
            bf16x8 bh1 = __builtin_bit_cast(bf16x8, P[h][2]);
            bf16x8 bl1 = __builtin_bit_cast(bf16x8, P[h][3]);
            const int kg = (kt + h) * 16 + m;
            const float wsqv = swsq[kg];
            if (kt + h + 2 < 32) {
                const uint4* np = wpack + (size_t)(kt + h + 2) * 256;
#pragma unroll
                for (int q = 0; q < 4; ++q) P[h][q] = np[q * 64 + lane];
            }
#pragma unroll
            for (int rt = 0; rt < 2; ++rt) {
                f32x4 acc = {0.f, 0.f, 0.f, 0.f};
                acc = __builtin_amdgcn_mfma_f32_16x16x32_bf16(afr[rt][0][0], bh0, acc, 0, 0, 0);
                acc = __builtin_amdgcn_mfma_f32_16x16x32_bf16(afr[rt][0][0], bl0, acc, 0, 0, 0);
                acc = __builtin_amdgcn_mfma_f32_16x16x32_bf16(afr[rt][0][1], bh0, acc, 0, 0, 0);
                acc = __builtin_amdgcn_mfma_f32_16x16x32_bf16(afr[rt][1][0], bh1, acc, 0, 0, 0);
                acc = __builtin_amdgcn_mfma_f32_16x16x32_bf16(afr[rt][1][0], bl1, acc, 0, 0, 0);
                acc = __builtin_amdgcn_mfma_f32_16x16x32_bf16(afr[rt][1][1], bh1, acc, 0, 0, 0);
#pragma unroll
                for (int r = 0; r < 4; ++r) {
                    float s = fmaf(-2.f, acc[r], wsqv);
                    bool lt1 = s < min1[rt][r];
                    bool lt2 = s < min2[rt][r];
                    min3[rt][r] = __builtin_amdgcn_fmed3f(min2[rt][r], min3[rt][r], s);
                    idx2[rt][r] = lt1 ? idx1[rt][r] : (lt2 ? kg : idx2[rt][r]);
                    min2[rt][r] = __builtin_amdgcn_fmed3f(min1[rt][r], min2[rt][r], s);
                    idx1[rt][r] = lt1 ? kg : idx1[rt][r];
                    min1[rt][r] = fminf(min1[rt][r], s);
                }
            }
        }
    }

    // Per-rowslot resolution: gmin reduce, candidate exact chains, u64 reduce.
#pragma unroll 1
    for (int rt = 0; rt < 2; ++rt)
#pragma unroll 1
        for (int r = 0; r < 4; ++r) {
            float g1 = min1[rt][r]; int gi = idx1[rt][r];
#pragma unroll
            for (int d = 1; d < 16; d <<= 1) {
                float og = __shfl_xor(g1, d);
                int   oi = __shfl_xor(gi, d);
                if (og < g1) { g1 = og; gi = oi; }
            }
            const float lim = g1 + MARGIN;
            const bool c1 = min1[rt][r] <= lim;
            const bool c2 = min2[rt][r] <= lim;
            const bool f3 = min3[rt][r] <= lim;
            unsigned long long b1 = __ballot(c1);
            unsigned long long b2 = __ballot(c2);
            unsigned long long b3 = __ballot(f3);
            const unsigned fld1 = (unsigned)(b1 >> (quad * 16)) & 0xFFFFu;
            const unsigned fld2 = (unsigned)(b2 >> (quad * 16)) & 0xFFFFu;
            const unsigned fld3 = (unsigned)(b3 >> (quad * 16)) & 0xFFFFu;
            const int  nc   = __popc(fld1) + __popc(fld2);
            const bool flag = fld3 != 0;   // >=3 same-class within M: rescan
            const int rowL = wvid * 32 + rt * 16 + quad * 4 + r;
            unsigned long long best = ~0ull;
            if (!flag && nc > 1) {
                const float* xr = &xs[rowL * 65];
                const float xq = sxsq[rowL];
                const int k1 = c1 ? idx1[rt][r] : idx2[rt][r];
                if (c1 || c2) best = eval_chain(xr, xq, w, swsq[k1], k1);
                if (c1 && c2) {
                    unsigned long long e =
                        eval_chain(xr, xq, w, swsq[idx2[rt][r]], idx2[rt][r]);
                    best = e < best ? e : best;
                }
            }
#pragma unroll
            for (int d = 1; d < 16; d <<= 1) {
                unsigned long long o = __shfl_xor(best, d);
                best = o < best ? o : best;
            }
            if (m == 0) {
                if (flag) rlist[atomicAdd(&rcount, 1)] = rowL;
                else sidx[rowL] = (nc > 1) ? (int)(best & 0xFFFFFFFFull) : gi;
            }
        }
    __syncthreads();   // sidx (candidate path) + rlist/rcount ready

    // Full exact rescan for flagged rows (rare, ~0.3%): whole block, 2 k/thr.
    const int rc = rcount;
#pragma unroll 1
    for (int i = 0; i < rc; ++i) {
        const int rowL = rlist[i];
        const float* xr = &xs[rowL * 65];
        const float xq = sxsq[rowL];
        unsigned long long bb = eval_chain(xr, xq, w, swsq[tid], tid);
        unsigned long long e2 = eval_chain(xr, xq, w, swsq[tid + 256], tid + 256);
        if (e2 < bb) bb = e2;
#pragma unroll
        for (int d = 1; d < 64; d <<= 1) {
            unsigned long long o = __shfl_xor(bb, d);
            if (o < bb) bb = o;
        }
        if (lane == 0) rred[wvid] = bb;
        __syncthreads();
        if (tid == 0) {
            unsigned long long q0 = rred[0] < rred[1] ? rred[0] : rred[1];
            unsigned long long q1 = rred[2] < rred[3] ? rred[2] : rred[3];
            sidx[rowL] = (int)((q0 < q1 ? q0 : q1) & 0xFFFFFFFFull);
        }
        __syncthreads();
    }

    // Epilogue: thread (rb=tid&127, cg=tid>>7) handles 32 channels of row rb;
    // x from LDS (no global re-read). Histogram: ONE direct atomic per row
    // to this block's replica.
    {
        const int rb = tid & 127, cg = tid >> 7;
        const int bk = sidx[rb];
        const float* xr = &xs[rb * 65];
        float dsum = 0.f;
        const float4* wb = (const float4*)(w + (size_t)bk * DIM + cg * 32);
        float* oq = out_q + (size_t)b * 262144 + hw0 + rb;
        if (cg == 0) {
            out_idx[n0 + rb] = (float)bk;
            atomicAdd(&counts[((blockIdx.x & rep_mask) << 9) + bk], 1u);
        }
#pragma unroll
        for (int j4 = 0; j4 < 8; ++j4) {
            float4 v = wb[j4];
            const int c = cg * 32 + j4 * 4;
            float e0 = v.x - xr[c + 0];
            float e1 = v.y - xr[c + 1];
            float e2 = v.z - xr[c + 2];
            float e3 = v.w - xr[c + 3];
            dsum = fmaf(e0, e0, dsum);
            dsum = fmaf(e1, e1, dsum);
            dsum = fmaf(e2, e2, dsum);
            dsum = fmaf(e3, e3, dsum);
            oq[(size_t)(c + 0) * 4096] = v.x;
            oq[(size_t)(c + 1) * 4096] = v.y;
            oq[(size_t)(c + 2) * 4096] = v.z;
            oq[(size_t)(c + 3) * 4096] = v.w;
        }
#pragma unroll
        for (int off = 32; off > 0; off >>= 1) dsum += __shfl_down(dsum, off);
        if (lane == 0) wred[wvid] = dsum;
    }
    __syncthreads();
    if (tid == 0)
        atomicAdd(loss_sum, (wred[0] + wred[1]) + (wred[2] + wred[3]));
}

// Final: original verified 512-thread reduction tree. Plain loads —
// dispatch ordering on the stream makes phase1's atomics visible, exactly
// as in the original (pre-fusion) validated structure. Replica sum is an
// exact integer sum feeding the bitwise-identical tree.
__global__ __launch_bounds__(512) void vq_final(
        const unsigned* __restrict__ counts,
        const float* __restrict__ loss_sum,
        float* __restrict__ out,
        int rep_mask) {
    __shared__ float red[8];
    const int tid = threadIdx.x;
    unsigned cnt = 0;
    for (int rr = 0; rr <= rep_mask; ++rr)
        cnt += counts[(rr << 9) + tid];
    float p = (float)cnt * (1.f / (float)NROWS);  // /131072 exact
    float t = p * logf(p + 1e-10f);
#pragma unroll
    for (int off = 32; off > 0; off >>= 1) t += __shfl_down(t, off);
    if ((tid & 63) == 0) red[tid >> 6] = t;
    __syncthreads();
    if (tid == 0) {
        float s = 0.f;
#pragma unroll
        for (int i = 0; i < 8; ++i) s += red[i];
        out[PERP_OFF] = expf(-s);
        // loss = q_latent + 0.25*e_latent = 1.25 * MSE (forward values equal)
        out[0] = loss_sum[0] * (1.25f / (float)NELEM);
    }
}

extern "C" void kernel_launch(void* const* d_in, const int* in_sizes, int n_in,
                              void* d_out, int out_size, void* d_ws, size_t ws_size,
                              hipStream_t stream) {
    const float* x = (const float*)d_in[0];
    const float* w = (const float*)d_in[1];
    float* out = (float*)d_out;
    char* ws = (char*)d_ws;

    // Histogram replica count: 8 (= XCD count; replica r only touched by
    // XCD r under round-robin dispatch). Degrade to 4/2 if workspace tight.
    int rep = 8;
    while (rep > 2 && (size_t)(64 + rep * 2048 + 2048 + 131072) > ws_size)
        rep >>= 1;

    float*    loss_sum = (float*)ws;
    unsigned* counts   = (unsigned*)(ws + 64);
    float*    swsq_g   = (float*)(ws + 64 + rep * 2048);
    unsigned short* wpack = (unsigned short*)(ws + 64 + rep * 2048 + 2048);

    // No memset dispatch: vq_prep zeroes loss/counts.
    vq_prep<<<32, 256, 0, stream>>>(w, swsq_g, wpack, counts, rep * 512,
                                    loss_sum);
    vq_phase1<<<NROWS / 128, 256, 0, stream>>>(x, w, swsq_g, (const uint4*)wpack,
                                               out, loss_sum, counts, rep - 1);
    vq_final<<<1, 512, 0, stream>>>(counts, loss_sum, out, rep - 1);
}